// Round 11
// baseline (855.353 us; speedup 1.0000x reference)
//
#include <hip/hip_runtime.h>
#include <math.h>

#define B_  8
#define L_  2500
#define D_  512
#define Y_  8921
#define LP  2560    // L padded
#define YP  8960    // Y padded to 140*64

// ws layout: fp16 X[B_][LP][D_]
//          | G fragment-major for 32x32x16: [yt(140)][kg(32)][mt(4)][lane(64)][8]
//            ROW-PARITY pairing inside each 32-row tile: row 2k = U(y),
//            row 2k+1 = F(y), y = yt*64 + mt*16 + k
// then fp32  denG[B_][YP] | numG[B_][YP]
#define WS_F16_HALVES  (B_ * LP * D_ + 2 * YP * D_)
#define ACC_FLOATS     (2 * B_ * YP)

typedef _Float16 f16x8  __attribute__((ext_vector_type(8)));
typedef float    f32x16 __attribute__((ext_vector_type(16)));

__device__ __forceinline__ void load_lds16(const _Float16* g, _Float16* l) {
  __builtin_amdgcn_global_load_lds(
      (const __attribute__((address_space(1))) unsigned int*)g,
      (__attribute__((address_space(3))) unsigned int*)l, 16, 0, 0);
}

__global__ void k_convert(const float* __restrict__ x,
                          const float* __restrict__ Uw,
                          const float* __restrict__ Fw,
                          _Float16* __restrict__ ws,
                          float* __restrict__ loss_slot) {
  if (blockIdx.x == 0 && threadIdx.x == 0) *loss_slot = 0.0f;
  const int NX = B_ * LP * (D_ / 8);   // 1310720 slots
  int idx = blockIdx.x * 256 + threadIdx.x;
  if (idx < ACC_FLOATS) ((float*)(ws + WS_F16_HALVES))[idx] = 0.0f;
  const float* src = nullptr;
  if (idx < NX) {
    int b  = idx / (LP * 64);
    int r  = idx - b * (LP * 64);
    int l  = r >> 6;
    int d8 = r & 63;
    if (l < L_) src = x + (((long)b * L_ + l) * D_ + d8 * 8);
  } else {
    // G fragment-major slot for 32x32x16 MFMA: [yt][kg][mt][lane]
    // A-fragment: row = lane&31 (within 32-row tile), k = kg*16 + (lane>>5)*8 + j
    int u    = idx - NX;
    int yt   = u >> 13;              // 8192 slots per yt (32*4*64)
    int w    = u & 8191;
    int lane = w & 63;
    int mt   = (w >> 6) & 3;         // m-tile of 32 rows
    int kg   = w >> 8;               // k granule of 16 (0..31)
    int row32 = lane & 31;
    int h     = lane >> 5;
    int y  = yt * 64 + mt * 16 + (row32 >> 1);   // ROW-PARITY pairing
    int k8 = kg * 2 + h;                          // 8-elem k granule
    if (y < Y_) src = (((row32 & 1) == 0) ? Uw : Fw) + (long)y * D_ + k8 * 8;
  }
  f16x8 o;
  if (src) {
    const float4* s4 = (const float4*)src;
    float4 a = s4[0], c = s4[1];
    o[0] = (_Float16)a.x; o[1] = (_Float16)a.y; o[2] = (_Float16)a.z; o[3] = (_Float16)a.w;
    o[4] = (_Float16)c.x; o[5] = (_Float16)c.y; o[6] = (_Float16)c.z; o[7] = (_Float16)c.w;
  } else {
    for (int i = 0; i < 8; ++i) o[i] = (_Float16)0.0f;
  }
  ((f16x8*)ws)[idx] = o;
}

// Round 11: 32x32x16 MFMA on the round-10 base (best: 378 µs, MfmaUtil 46).
// Round-10 confirmed the serial-pipes model 1:1 (VALU cycles removed == wall
// cycles removed). Largest remaining term = matrix pipe (46%). 32x32x16 runs
// at 2382 vs 2075 TF (17% fewer matrix cycles for the same FLOPs) and halves
// MFMA instruction count. Isomorphic mapping: wave tile 64G x 128l = 2x4
// tiles of 32x32, acc[2][4] f32x16 = 128 AGPR (unchanged), same XT layout +
// XOR swizzle (reader granule (ksub*2+h)^r7, still 2-way-free), same au/bx
// op counts. C/D: col=lane&31, row=(reg&3)+8(reg>>2)+4(lane>>5) — U/F
// row-parity gives same-lane (S,C) in reg pairs (4q+2j, 4q+2j+1). A/B:
// row/col=lane&31, k=(lane>>5)*8+j (extension of the proven 16x16 mapping).
__global__ __launch_bounds__(128, 2)
void k_attn(const _Float16* __restrict__ ws,
            float* __restrict__ accG) {
  __shared__ __align__(16) _Float16 XT[8192];   // 128 rows x 64 halves

  const int tid  = threadIdx.x;
  const int lane = tid & 63;
  const int wave = tid >> 6;           // 0..1
  const int wy = wave;                 // G-half (64 G rows = 2 m-tiles = 32 y)
  const int bid = blockIdx.x;          // 0..4479
  const int b   = bid & 7;             // XCD id (dispatch: bid % 8)
  const int lq  = (bid >> 3) & 3;      // l quarter (640 cols)
  const int yt  = bid >> 5;            // 0..139 (64 labels each)

  const _Float16* Xg = ws + (long)b * LP * D_ + (long)lq * 640 * D_;
  // G base: + yt block + this wave's first m-tile (wy*2) + lane
  const _Float16* Gw = ws + (long)B_ * LP * D_ + (long)yt * 65536
                          + (wy * 2) * 512 + lane * 8;

  // X staging: 16 segments of 1KB (8 rows x 64 halves); 8 per wave
  const int srow = lane >> 3;
  const int sg8  = ((lane & 7) ^ srow) * 8;
  const _Float16* xsrc[8];
  _Float16*       xdst[8];
  #pragma unroll
  for (int i = 0; i < 8; ++i) {
    int seg = wave * 8 + i;
    xsrc[i] = Xg + (long)(seg * 8 + srow) * D_ + sg8;   // + lt*128 rows later
    xdst[i] = XT + seg * 512;
  }

  // compute geometry
  const int xrow32 = lane & 31;        // B col (l within 32-col tile)
  const int r7     = lane & 7;
  const int h      = lane >> 5;        // k-granule half

  float redD[2][4][2], redN[2][4][2];  // per (mt, q, j): y = mt*16+4q+2h+j
  #pragma unroll
  for (int mt = 0; mt < 2; ++mt)
    for (int q = 0; q < 4; ++q)
      for (int j = 0; j < 2; ++j) { redD[mt][q][j] = 0.0f; redN[mt][q][j] = 0.0f; }

  for (int lt = 0; lt < 5; ++lt) {
    f32x16 acc[2][4];
    #pragma unroll
    for (int mt = 0; mt < 2; ++mt)
      for (int nt = 0; nt < 4; ++nt)
        #pragma unroll
        for (int v = 0; v < 16; ++v) acc[mt][nt][v] = 0.0f;
    const long xofs = (long)lt * 128 * D_;
    for (int kkstep = 0; kkstep < 8; ++kkstep) {
      // A-fragments direct from global (L2) — issued before the barriers so
      // their latency hides under the X stage + drain window
      f16x8 au[4][2];
      #pragma unroll
      for (int ksub = 0; ksub < 4; ++ksub)
        #pragma unroll
        for (int mt = 0; mt < 2; ++mt)
          au[ksub][mt] = *(const f16x8*)(Gw + (size_t)kkstep * 8192 + ksub * 2048 + mt * 512);
      __syncthreads();
      #pragma unroll
      for (int i = 0; i < 8; ++i)
        load_lds16(xsrc[i] + xofs + kkstep * 64, xdst[i]);
      __syncthreads();
      #pragma unroll
      for (int ksub = 0; ksub < 4; ++ksub) {
        const int off = (((ksub * 2 + h) ^ r7) * 8);
        f16x8 bx[4];
        #pragma unroll
        for (int nt = 0; nt < 4; ++nt)
          bx[nt] = *(const f16x8*)&XT[(xrow32 + nt * 32) * 64 + off];
        #pragma unroll
        for (int mt = 0; mt < 2; ++mt)
          #pragma unroll
          for (int nt = 0; nt < 4; ++nt)
            acc[mt][nt] = __builtin_amdgcn_mfma_f32_32x32x16_f16(
                au[ksub][mt], bx[nt], acc[mt][nt], 0, 0, 0);
      }
    }
    // epilogue (same-lane): per tile, reg pairs (4q+2j, 4q+2j+1) hold (S,C)
    // of y_local = 4q + 2h + j. Pad cols: S=C=0 -> e=1 exact; k_final
    // subtracts LP-L_.
    #pragma unroll
    for (int mt = 0; mt < 2; ++mt)
      #pragma unroll
      for (int nt = 0; nt < 4; ++nt)
        #pragma unroll
        for (int q = 0; q < 4; ++q)
          #pragma unroll
          for (int j = 0; j < 2; ++j) {
            float e = __expf(acc[mt][nt][q * 4 + 2 * j]);
            redD[mt][q][j] += e;
            redN[mt][q][j] += e * acc[mt][nt][q * 4 + 2 * j + 1];
          }
  }

  // reduce over the 32 columns sharing each label row
  for (int m = 1; m < 32; m <<= 1)
    #pragma unroll
    for (int mt = 0; mt < 2; ++mt)
      for (int q = 0; q < 4; ++q)
        for (int j = 0; j < 2; ++j) {
          redD[mt][q][j] += __shfl_xor(redD[mt][q][j], m, 64);
          redN[mt][q][j] += __shfl_xor(redN[mt][q][j], m, 64);
        }
  if ((lane & 31) == 0) {
    #pragma unroll
    for (int mt = 0; mt < 2; ++mt)
      for (int q = 0; q < 4; ++q)
        for (int j = 0; j < 2; ++j) {
          int y = yt * 64 + wy * 32 + mt * 16 + q * 4 + h * 2 + j;
          atomicAdd(&accG[b * YP + y], redD[mt][q][j]);
          atomicAdd(&accG[B_ * YP + b * YP + y], redN[mt][q][j]);
        }
  }
}

__global__ void k_final(const float* __restrict__ accG,
                        const float* __restrict__ fb,
                        float* __restrict__ out) {
  int id = blockIdx.x * 256 + threadIdx.x;
  if (id >= B_ * Y_) return;
  int b = id / Y_, y = id - b * Y_;
  float den = accG[b * YP + y] - (float)(LP - L_);
  out[id] = accG[B_ * YP + b * YP + y] / den + fb[y];
}

__global__ void k_loss(const float* __restrict__ y,
                       const float* __restrict__ t,
                       float* __restrict__ loss) {
  float p = 0.0f;
  for (int i = blockIdx.x * 256 + threadIdx.x; i < B_ * Y_; i += gridDim.x * 256) {
    float v = y[i], tg = t[i];
    p += fmaxf(v, 0.0f) - v * tg + log1pf(__expf(-fabsf(v)));
  }
  for (int m = 32; m; m >>= 1) p += __shfl_down(p, m, 64);
  __shared__ float wsum[4];
  int lane = threadIdx.x & 63, wv = threadIdx.x >> 6;
  if (lane == 0) wsum[wv] = p;
  __syncthreads();
  if (threadIdx.x == 0) {
    float s = wsum[0] + wsum[1] + wsum[2] + wsum[3];
    atomicAdd(loss, s * (1.0f / (float)(B_ * Y_)));
  }
}

extern "C" void kernel_launch(void* const* d_in, const int* in_sizes, int n_in,
                              void* d_out, int out_size, void* d_ws, size_t ws_size,
                              hipStream_t stream) {
  (void)in_sizes; (void)n_in; (void)out_size; (void)ws_size;
  const float* x       = (const float*)d_in[0];
  const float* target  = (const float*)d_in[1];
  const float* U_w     = (const float*)d_in[3];
  const float* final_w = (const float*)d_in[4];
  const float* final_b = (const float*)d_in[5];
  float* out = (float*)d_out;
  _Float16* ws = (_Float16*)d_ws;
  float* accG = (float*)(ws + WS_F16_HALVES);

  k_convert<<<9600, 256, 0, stream>>>(x, U_w, final_w, ws, out + B_ * Y_);

  k_attn<<<4480, 128, 0, stream>>>(ws, accG);

  k_final<<<(B_ * Y_ + 255) / 256, 256, 0, stream>>>(accG, final_b, out);
  k_loss<<<140, 256, 0, stream>>>(out, target, out + B_ * Y_);
}